// Round 16
// baseline (402.050 us; speedup 1.0000x reference)
//
#include <hip/hip_runtime.h>
#include <hip/hip_bf16.h>
#include <hip/hip_fp8.h>

#define NEG_SLOPE 0.01f
#define CH 4096            // edges per block in hist/scatter (LDS-aggregated)
#define PAD 16             // 64B stride for contended global counters
// Dual bucket sort: row-bucketed CSR for the gather, col-bucketed staging for
// the presum (cw) aggregation -> NO per-edge global atomics in the hot path.
// bucket id = id >> 8 (256 ids per bucket); NB = ceil(N/256) <= 512.
// Packing: {other_id (<2^24) | low8(key_id) << 24}.
// scatter2: in-block LDS counting sort so staging writes stream out as
// contiguous runs per bucket (evidence R3->R4: fixed 4x write amplification).
// R11 LESSON (do not retry): CH=12288/SB=512 regressed. scatter2 ~97us PARKED
// (pattern-bound; occupancy-insensitive; CH=4096 is the 3-block/CU optimum).
// rowfin: fused rowdeg+rowsort, IN-PLACE (sorted overlays stagingR); ebuf
// packed to 4B (col17|mag15, sign implicit). R15 evidence: 2x occupancy gave
// only -4us -> rowfin PARKED (not the hidden cost).
// R16: col_finalize was 391 blocks = 6 waves/CU (grid-limited, same defect
// class as R8/R11) -> sliced: CSL=8 blocks per bucket, LDS partial bins,
// one global f32 atomic per (slice, col). 800K spread atomics << R2 ceiling.
// Bucket size ~ Binomial(3.2M, 256/1e5): mean 8192, sigma 90; CAP=9216=+11sig.
// ORDERING: rowfin -> col_finalize (stagingC+dinv) -> h1 (regB over stagingC)
//           -> gather (sorted regA, h1q regB) -> h2pool.
// h1q is FP8 e4m3 (row 32B): gather footprint 3.2MB, L2-resident (R13: -13us).
// h1 kept ONLY as bf16 pairs (h2pool's sole stream); p1b bf16; accum fp32.
// h2pool v2 (feature-per-lane): weight columns in VGPRs, pooled sums in regs.
// R8 LESSON (do not retry): block-per-bucket LDS-accumulating GATHER collapsed
// parallelism -> 679us. Random-gather needs ~400K independent threads.
#define NT 32              // col tiles (col < 2^17 -> tile = col>>12 in [0,32))
#define TILE_SHIFT 12      // tile-sorted rows keep the gather window compact
#define KEYS (256 * NT)    // row-sort bins: (rowlow, tile)
#define CAP 9216           // rowfin LDS staging capacity (entries per bucket)
#define CSL 8              // col_finalize slices per bucket (grid 391->3128)
#define H2B 512            // h2pool grid (2048 waves, grid-stride over nodes)
#define NREP 16            // sbuf replicas (atomic contention divider)

__device__ __forceinline__ void atomAddF(float* p, float v) {
    unsafeAtomicAdd(p, v);
}

// bf16 pack/unpack (round-to-nearest-even; finite values only)
__device__ __forceinline__ unsigned bf16rn(float f) {
    unsigned u = __float_as_uint(f);
    return (u + 0x7FFFu + ((u >> 16) & 1u)) >> 16;
}
__device__ __forceinline__ unsigned pack2(float a, float b) {
    return bf16rn(a) | (bf16rn(b) << 16);
}
__device__ __forceinline__ float blo(unsigned u) { return __uint_as_float(u << 16); }
__device__ __forceinline__ float bhi(unsigned u) { return __uint_as_float(u & 0xFFFF0000u); }

// fp8 e4m3 (OCP) encode/decode via HIP type
__device__ __forceinline__ unsigned char e8(float f) {
    __hip_fp8_e4m3 q(f);
    return (unsigned char)q.__x;
}
__device__ __forceinline__ float d8(unsigned w, int b) {
    __hip_fp8_e4m3 q;
    q.__x = (__hip_fp8_storage_t)((w >> (b * 8)) & 0xFF);
    return (float)q;
}

// wave-inclusive scan of v (64 lanes)
__device__ __forceinline__ int waveInclScan(int v, int lane) {
#pragma unroll
    for (int off = 1; off < 64; off <<= 1) {
        int u = __shfl_up(v, off);
        if (lane >= off) v += u;
    }
    return v;
}

// ---- phase 1: dual bucket histogram (row and col), block-aggregated -----
__global__ void hist2_kernel(const int* __restrict__ row, const int* __restrict__ col,
                             int* __restrict__ bhR, int* __restrict__ bhC, int E, int NB) {
    __shared__ int lhR[512];
    __shared__ int lhC[512];
    for (int t = threadIdx.x; t < 512; t += 256) { lhR[t] = 0; lhC[t] = 0; }
    __syncthreads();
    int base = blockIdx.x * CH;
    int end = min(base + CH, E);
    for (int e = base + threadIdx.x; e < end; e += 256) {
        atomicAdd(&lhR[row[e] >> 8], 1);
        atomicAdd(&lhC[col[e] >> 8], 1);
    }
    __syncthreads();
    for (int t = threadIdx.x; t < NB; t += 256) {
        if (lhR[t]) atomicAdd(&bhR[t * PAD], lhR[t]);
        if (lhC[t]) atomicAdd(&bhC[t * PAD], lhC[t]);
    }
}

// ---- phase 2: exclusive scans of both bucket-count arrays (one launch) --
// block 0: R side (+ rowptr[N] = E); block 1: C side.
__global__ void bucket_scan2_kernel(const int* __restrict__ bhR, const int* __restrict__ bhC,
                                    int* __restrict__ bbaseR, int* __restrict__ bbaseC,
                                    int* __restrict__ bcurR, int* __restrict__ bcurC,
                                    int* __restrict__ rowptr, int NB, int N, int E) {
    const int* bh = blockIdx.x ? bhC : bhR;
    int* bbase    = blockIdx.x ? bbaseC : bbaseR;
    int* bcur     = blockIdx.x ? bcurC : bcurR;
    __shared__ int s[512];
    int t = threadIdx.x;
    int v = (t < NB) ? bh[t * PAD] : 0;
    s[t] = v;
    __syncthreads();
    for (int off = 1; off < 512; off <<= 1) {
        int x = (t >= off) ? s[t - off] : 0;
        __syncthreads();
        s[t] += x;
        __syncthreads();
    }
    if (t < NB) { bbase[t] = s[t] - v; bcur[t * PAD] = s[t] - v; }
    if (t == 0) {
        bbase[NB] = E;
        if (blockIdx.x == 0) rowptr[N] = E;
    }
}

// ---- phase 3: dual scatter with in-block LDS counting sort --------------
// stagingR (row-bucketed): {col | rowlow<<24, attr}
// stagingC (col-bucketed): {row | collow<<24, attr}
__global__ void __launch_bounds__(256, 1)
scatter2_kernel(const int* __restrict__ row, const int* __restrict__ col,
                const float* __restrict__ attr,
                int* __restrict__ bcurR, int* __restrict__ bcurC,
                int2* __restrict__ stagingR, int2* __restrict__ stagingC,
                int E, int NB) {
    __shared__ int lh[512];
    __shared__ int lbase[512];
    __shared__ int loff[512];
    __shared__ int lcur[512];
    __shared__ int wsum[4];
    __shared__ int2 buf[CH];              // 32KB: block's edges grouped by bucket
    __shared__ unsigned short bkid[CH];   // 8KB: bucket id per entry
    int t = threadIdx.x;
    int lane = t & 63, wv = t >> 6;
    int base = blockIdx.x * CH;
    int end = min(base + CH, E);
    int cnt = end - base;

    for (int side = 0; side < 2; side++) {
        const int* key   = side ? col : row;
        const int* other = side ? row : col;
        int* bcur        = side ? bcurC : bcurR;
        int2* out        = side ? stagingC : stagingR;
        // hist
        for (int k = t; k < 512; k += 256) { lh[k] = 0; lcur[k] = 0; }
        __syncthreads();
        for (int e = base + t; e < end; e += 256)
            atomicAdd(&lh[key[e] >> 8], 1);
        __syncthreads();
        // reserve global runs
        for (int k = t; k < NB; k += 256)
            if (lh[k]) lbase[k] = atomicAdd(&bcur[k * PAD], lh[k]);
        // local exclusive scan of lh[0..511]: pair per thread, shfl wave scan
        int a0 = lh[2 * t], a1 = lh[2 * t + 1];
        int psum = a0 + a1;
        int incl = waveInclScan(psum, lane);
        if (lane == 63) wsum[wv] = incl;
        __syncthreads();
        int wadd = 0;
        for (int w = 0; w < wv; w++) wadd += wsum[w];
        int pexcl = incl + wadd - psum;
        loff[2 * t] = pexcl;
        loff[2 * t + 1] = pexcl + a0;
        __syncthreads();
        // place into LDS grouped by bucket
        for (int e = base + t; e < end; e += 256) {
            int k = key[e], o = other[e];
            int bk = k >> 8;
            int rank = atomicAdd(&lcur[bk], 1);
            int lpos = loff[bk] + rank;
            buf[lpos] = make_int2(o | ((k & 255) << 24), __float_as_int(attr[e]));
            bkid[lpos] = (unsigned short)bk;
        }
        __syncthreads();
        // coalesced write-out: consecutive j -> consecutive dst within runs
        for (int j = t; j < cnt; j += 256) {
            int bk = bkid[j];
            out[lbase[bk] + (j - loff[bk])] = buf[j];
        }
        __syncthreads();
    }
}

// ---- phase 4a: fused degree + counting sort, IN-PLACE -------------------
// Block b owns bucket b = rows [b*256, b*256+256) exclusively.
// ebuf entry: col(17b) | bf16rn(dinv*attr)(15b, sign implicit negative).
__global__ void __launch_bounds__(256, 1)
rowfin_kernel(const int* __restrict__ bbaseR, const int2* __restrict__ stagingR,
              int2* __restrict__ sorted /*aliases stagingR*/,
              int* __restrict__ rowptr, float* __restrict__ dinv, int N) {
    __shared__ int lcount[KEYS];      // 32KB: counts -> cursors
    __shared__ unsigned ebuf[CAP];    // 36KB: packed sorted bucket staging
    __shared__ float ldeg[256];
    __shared__ float sdinv[256];
    __shared__ int wsum[4];
    int t = threadIdx.x;
    int lane = t & 63, wv = t >> 6;
    int b = blockIdx.x;
    int base = bbaseR[b], end = bbaseR[b + 1];
    int cnt = end - base;
    for (int k = t; k < KEYS; k += 256) lcount[k] = 0;
    ldeg[t] = 0.f;
    __syncthreads();
    // pass1: histogram + degree
    for (int e = base + t; e < end; e += 256) {
        int2 w = stagingR[e];
        int rl = (w.x >> 24) & 255;
        int tile = (w.x & 0xFFFFFF) >> TILE_SHIFT;
        atomicAdd(&lcount[rl * NT + tile], 1);
        atomicAdd(&ldeg[rl], __int_as_float(w.y));
    }
    __syncthreads();
    // per-row serial scan of NT bins; s = row total
    int vals[NT];
    int s = 0;
#pragma unroll
    for (int j = 0; j < NT; j++) { vals[j] = s; s += lcount[t * NT + j]; }
    int incl = waveInclScan(s, lane);
    if (lane == 63) wsum[wv] = incl;
    __syncthreads();
    int wadd = 0;
    for (int w = 0; w < wv; w++) wadd += wsum[w];
    int rowexcl = incl + wadd - s;
#pragma unroll
    for (int j = 0; j < NT; j++) lcount[t * NT + j] = rowexcl + vals[j];  // -> cursors
    int grow = (b << 8) + t;
    float d = ldeg[t];
    float di = d > 0.f ? rsqrtf(d) : 0.f;
    sdinv[t] = di;
    if (grow < N) {
        rowptr[grow] = base + rowexcl;
        dinv[grow] = di;
    }
    __syncthreads();
    // pass2: place packed {col|mag15<<17} into LDS at sorted pos (reads L2-hot)
    for (int e = base + t; e < end; e += 256) {
        int2 w = stagingR[e];
        int rl = (w.x >> 24) & 255;
        int c = w.x & 0xFFFFFF;
        int key = rl * NT + (c >> TILE_SHIFT);
        int pos = atomicAdd(&lcount[key], 1);
        float mag = sdinv[rl] * __int_as_float(w.y);   // >= 0
        unsigned pk = (unsigned)c | (bf16rn(mag) << 17);
        if (pos < CAP) ebuf[pos] = pk;
        else {  // statistically impossible (>mean+11sigma)
            unsigned m16 = (pk >> 17) << 16;
            sorted[base + pos] = make_int2(c, (int)(m16 | 0x80000000u));
        }
    }
    __syncthreads();
    // pass3: unpack + linear stream-out over the block's own (fully-read) range
    int lim = min(cnt, CAP);
    for (int j = t; j < lim; j += 256) {
        unsigned pk = ebuf[j];
        unsigned m16 = (pk >> 17) << 16;                   // bf16 magnitude bits
        sorted[base + j] = make_int2((int)(pk & 0x1FFFFu), (int)(m16 | 0x80000000u));
    }
}

// ---- phase 4b: per-col-bucket presum, SLICED (grid NB*CSL) --------------
// presum[c] += slice partial of sum_{e: col=c} -dinv[row_e] * attr_e
// 8 blocks per bucket -> ~12 waves/CU (was 6: grid-limited at NB=391).
// Runs after rowfin (needs dinv); MUST run before h1 (h1 overlays stagingC).
__global__ void col_finalize_kernel(const int* __restrict__ bbaseC,
                                    const int2* __restrict__ stagingC,
                                    const float* __restrict__ dinv,
                                    float* __restrict__ presum, int N) {
    __shared__ float bins[256];
    int t = threadIdx.x;
    int b  = blockIdx.x / CSL;      // bucket
    int sl = blockIdx.x % CSL;      // slice within bucket
    int base = bbaseC[b], end = bbaseC[b + 1];
    int cnt = end - base;
    int per = (cnt + CSL - 1) / CSL;
    int s0 = base + sl * per;
    int s1 = min(s0 + per, end);
    bins[t] = 0.f;
    __syncthreads();
    for (int e = s0 + t; e < s1; e += 256) {
        int2 w = stagingC[e];
        int r = w.x & 0xFFFFFF;
        int cl = (w.x >> 24) & 255;
        float pre = -dinv[r] * __int_as_float(w.y);
        atomicAdd(&bins[cl], pre);   // LDS float atomic
    }
    __syncthreads();
    int grow = (b << 8) + t;
    if (grow < N && bins[t] != 0.f) atomAddF(&presum[grow], bins[t]);
}

// ---- h1 = leaky_relu(x @ w1 + b1) ---------------------------------------
// Outputs: h1b (bf16 pairs, 64B/row: word w = feats 2w,2w+1) for h2pool,
//          h1q (fp8 e4m3 * dinv, 32B/row) for the gather.
__global__ void h1_kernel(const float* __restrict__ x, const float* __restrict__ w,
                          const float* __restrict__ b, const float* __restrict__ dinv,
                          uint4* __restrict__ h1b, uint4* __restrict__ h1q, int N) {
    __shared__ float ws[20 * 32];
    __shared__ float bs[32];
    for (int t = threadIdx.x; t < 640; t += blockDim.x) ws[t] = w[t];
    if (threadIdx.x < 32) bs[threadIdx.x] = b[threadIdx.x];
    __syncthreads();
    int i = blockIdx.x * blockDim.x + threadIdx.x;
    if (i >= N) return;
    float xi[20];
#pragma unroll
    for (int k = 0; k < 20; k++) xi[k] = x[i * 20 + k];
    float acc[32];
#pragma unroll
    for (int j = 0; j < 32; j++) acc[j] = bs[j];
#pragma unroll
    for (int k = 0; k < 20; k++) {
        float a = xi[k];
#pragma unroll
        for (int j = 0; j < 32; j++) acc[j] += a * ws[k * 32 + j];
    }
#pragma unroll
    for (int j = 0; j < 32; j++) {
        float v = acc[j];
        acc[j] = v > 0.f ? v : v * NEG_SLOPE;
    }
    unsigned u[16];
#pragma unroll
    for (int k = 0; k < 16; k++) u[k] = pack2(acc[2 * k], acc[2 * k + 1]);
#pragma unroll
    for (int q = 0; q < 4; q++)
        h1b[(long)i * 4 + q] = make_uint4(u[4 * q], u[4 * q + 1], u[4 * q + 2], u[4 * q + 3]);
    float di = dinv[i];
    unsigned wds[8];
#pragma unroll
    for (int wq = 0; wq < 8; wq++) {
        unsigned wd = 0;
#pragma unroll
        for (int j = 0; j < 4; j++)
            wd |= (unsigned)e8(di * acc[wq * 4 + j]) << (8 * j);
        wds[wq] = wd;
    }
    h1q[(long)i * 2 + 0] = make_uint4(wds[0], wds[1], wds[2], wds[3]);
    h1q[(long)i * 2 + 1] = make_uint4(wds[4], wds[5], wds[6], wds[7]);
}

// ---- pure gather-propagate (no atomics), fp8 operand --------------------
// p1[i] = sum_{e in CSR row i} pre_e * h1q[col_e]   (dinv[col] baked into h1q)
// 4 threads per node, each owning 8 fp8 features (one uint2 = 32B/row total).
__global__ void gather_kernel(const int* __restrict__ rowptr, const int2* __restrict__ sorted,
                              const uint2* __restrict__ h1q, uint4* __restrict__ p1b, int N) {
    long idx = (long)blockIdx.x * blockDim.x + threadIdx.x;
    int node = (int)(idx >> 2);
    int part = (int)(idx & 3);
    if (node >= N) return;
    int s0 = rowptr[node], s1 = rowptr[node + 1];
    float acc[8];
#pragma unroll
    for (int k = 0; k < 8; k++) acc[k] = 0.f;
    int e = s0;
    for (; e + 4 <= s1; e += 4) {
        int2 q0 = sorted[e], q1 = sorted[e + 1], q2 = sorted[e + 2], q3 = sorted[e + 3];
        float n0 = __int_as_float(q0.y), n1 = __int_as_float(q1.y);
        float n2 = __int_as_float(q2.y), n3 = __int_as_float(q3.y);
        uint2 v0 = h1q[(long)q0.x * 4 + part];
        uint2 v1 = h1q[(long)q1.x * 4 + part];
        uint2 v2 = h1q[(long)q2.x * 4 + part];
        uint2 v3 = h1q[(long)q3.x * 4 + part];
#pragma unroll
        for (int j = 0; j < 4; j++) {
            acc[j]     += n0 * d8(v0.x, j) + n1 * d8(v1.x, j) + n2 * d8(v2.x, j) + n3 * d8(v3.x, j);
            acc[4 + j] += n0 * d8(v0.y, j) + n1 * d8(v1.y, j) + n2 * d8(v2.y, j) + n3 * d8(v3.y, j);
        }
    }
    for (; e < s1; e++) {
        int2 q = sorted[e];
        float nm = __int_as_float(q.y);
        uint2 v = h1q[(long)q.x * 4 + part];
#pragma unroll
        for (int j = 0; j < 4; j++) {
            acc[j]     += nm * d8(v.x, j);
            acc[4 + j] += nm * d8(v.y, j);
        }
    }
    // p1b keeps the bf16 pair layout: word w holds features (2w, 2w+1).
    p1b[(long)node * 4 + part] = make_uint4(pack2(acc[0], acc[1]), pack2(acc[2], acc[3]),
                                            pack2(acc[4], acc[5]), pack2(acc[6], acc[7]));
}

// ---- fused h2 + pooled sums, v3: feature-per-lane, bf16 h1 + p1 ---------
// Lane l owns output feature j=l. w0col/w1col (32 floats each) live in regs.
// h1 and p1 rows are both 16 packed-bf16 words; lanes 0-15 hold word m=lane,
// shfl broadcasts word k>>1 (features k, k+1) to all lanes.
__global__ void __launch_bounds__(256, 1)
h2pool_kernel(const uint4* __restrict__ h1b, const uint4* __restrict__ p1b,
              const float* __restrict__ presum, const float* __restrict__ dinv,
              const float* __restrict__ w0, const float* __restrict__ w1,
              const float* __restrict__ b, float* __restrict__ sbuf, int N, int W) {
    __shared__ float wred[4][128];
    int t = threadIdx.x;
    int lane = t & 63, wv = t >> 6;
    float w0r[32], w1r[32];
#pragma unroll
    for (int k = 0; k < 32; k++) {
        w0r[k] = w0[k * 64 + lane];   // column j=lane of w2_0 (32x64 row-major)
        w1r[k] = w1[k * 64 + lane];
    }
    float bj = b[lane];
    const unsigned* h1w = (const unsigned*)h1b;
    const unsigned* p1w = (const unsigned*)p1b;
    float s1 = 0.f, s2 = 0.f;
    int gw = blockIdx.x * 4 + wv;     // global wave id; W = total waves
    for (int i = gw; i < N; i += W) {
        unsigned hw = h1w[(long)i * 16 + (lane & 15)];  // lane m holds h1 word m
        unsigned pw = p1w[(long)i * 16 + (lane & 15)];  // lane m holds p1 word m
        float cwi = presum[i] * dinv[i];                // uniform -> broadcast
        float a0 = bj, a1 = 0.f, a2 = 0.f, a3 = 0.f;
#pragma unroll
        for (int k = 0; k < 32; k += 4) {
            unsigned hA = __shfl(hw, k >> 1);       // h1 features k, k+1
            unsigned hB = __shfl(hw, (k >> 1) + 1); // h1 features k+2, k+3
            unsigned pA = __shfl(pw, k >> 1);       // p1 features k, k+1
            unsigned pB = __shfl(pw, (k >> 1) + 1); // p1 features k+2, k+3
            a0 += blo(hA) * w0r[k]     + blo(pA) * w1r[k];
            a1 += bhi(hA) * w0r[k + 1] + bhi(pA) * w1r[k + 1];
            a2 += blo(hB) * w0r[k + 2] + blo(pB) * w1r[k + 2];
            a3 += bhi(hB) * w0r[k + 3] + bhi(pB) * w1r[k + 3];
        }
        float v = (a0 + a1) + (a2 + a3);
        v = v > 0.f ? v : v * NEG_SLOPE;
        s1 += v;
        s2 += cwi * v;
    }
    wred[wv][lane] = s1;
    wred[wv][64 + lane] = s2;
    __syncthreads();
    if (t < 128) {
        float s = wred[0][t] + wred[1][t] + wred[2][t] + wred[3][t];
        atomAddF(&sbuf[(blockIdx.x & (NREP - 1)) * 128 + t], s);
    }
}

// ---- pooled = (s1/N)@w30 + (s2/N)@w31 + b3; out = log_softmax -----------
__global__ void final_kernel(const float* __restrict__ sbuf,
                             const float* __restrict__ w30, const float* __restrict__ w31,
                             const float* __restrict__ b3, float* __restrict__ out, float invN) {
    __shared__ float s1s[64];
    __shared__ float s2s[64];
    int t = threadIdx.x;
    float s1 = 0.f, s2 = 0.f;
#pragma unroll
    for (int r = 0; r < NREP; r++) {
        s1 += sbuf[r * 128 + t];
        s2 += sbuf[r * 128 + 64 + t];
    }
    s1s[t] = s1;
    s2s[t] = s2;
    __syncthreads();
    if (t != 0) return;
    float p[2];
    for (int c = 0; c < 2; c++) {
        float a = 0.f;
        for (int k = 0; k < 64; k++) a += s1s[k] * w30[k * 2 + c] + s2s[k] * w31[k * 2 + c];
        p[c] = a * invN + b3[c];
    }
    float m = fmaxf(p[0], p[1]);
    float lse = m + logf(expf(p[0] - m) + expf(p[1] - m));
    out[0] = p[0] - lse;
    out[1] = p[1] - lse;
}

extern "C" void kernel_launch(void* const* d_in, const int* in_sizes, int n_in,
                              void* d_out, int out_size, void* d_ws, size_t ws_size,
                              hipStream_t stream) {
    const float* x    = (const float*)d_in[0];
    const int*   ei   = (const int*)d_in[1];
    const float* attr = (const float*)d_in[2];
    const float* w1_0 = (const float*)d_in[3];
    const float* b1   = (const float*)d_in[4];
    const float* w2_0 = (const float*)d_in[5];
    const float* w2_1 = (const float*)d_in[6];
    const float* b2   = (const float*)d_in[7];
    const float* w3_0 = (const float*)d_in[8];
    const float* w3_1 = (const float*)d_in[9];
    const float* b3   = (const float*)d_in[10];

    const int N = in_sizes[0] / 20;   // 100000
    const int E = in_sizes[2];        // 3200000
    const int* row = ei;
    const int* col = ei + E;
    const int NB = (N + 255) >> 8;    // 391 buckets (<= 512)

    // workspace layout (words)
    long big = (long)(2L * E > 64L * N ? 2L * E : 64L * N);
    float* ws = (float*)d_ws;
    float* dinv   = ws;                            // N
    float* presum = ws + N;                        // N (atomically accumulated)
    int*   rowptr = (int*)(ws + 2L * N);           // N+1 (alloc N+4)
    long   off    = 3L * N + 4;
    int*   bhR    = (int*)(ws + off); off += 512L * PAD;   // row hist (padded)
    int*   bhC    = (int*)(ws + off); off += 512L * PAD;   // col hist (padded)
    int*   bbaseR = (int*)(ws + off); off += 516;
    int*   bbaseC = (int*)(ws + off); off += 516;
    int*   bcurR  = (int*)(ws + off); off += 512L * PAD;
    int*   bcurC  = (int*)(ws + off); off += 512L * PAD;
    float* sbuf   = ws + off;         off += NREP * 128;   // replicated pooled sums
    long   offA   = (off + 15) & ~15L;                     // 64B-align regA
    float* regA   = ws + offA;                  // big: stagingR -> sorted (in-place)
    float* regB   = regA + big;                 // big: stagingC -> h1b+p1b+h1q

    int2*  stagingR = (int2*)regA;              // rewritten in-place as sorted
    int2*  sorted   = (int2*)regA;              // == stagingR region; dead after gather
    int2*  stagingC = (int2*)regB;              // dead after col_finalize
    uint4* h1b      = (uint4*)regB;             // bf16 pairs, 16N words (over stagingC)
    uint4* p1b      = (uint4*)(regB + 16L * N); // bf16, 16N words
    uint4* h1q      = (uint4*)(regB + 32L * N); // fp8 (dinv-scaled), 8N words

    // zero accumulated regions (ws is poisoned before every launch)
    hipMemsetAsync(bhR, 0, 2 * 512 * PAD * 4, stream);   // bhR + bhC contiguous
    hipMemsetAsync(presum, 0, (size_t)N * 4, stream);
    hipMemsetAsync(sbuf, 0, NREP * 128 * 4, stream);

    const int B = 256;
    const int NCH = (E + CH - 1) / CH;   // chunk-blocks for hist/scatter
    hist2_kernel<<<NCH, B, 0, stream>>>(row, col, bhR, bhC, E, NB);
    bucket_scan2_kernel<<<2, 512, 0, stream>>>(bhR, bhC, bbaseR, bbaseC, bcurR, bcurC,
                                               rowptr, NB, N, E);
    scatter2_kernel<<<NCH, B, 0, stream>>>(row, col, attr, bcurR, bcurC, stagingR, stagingC, E, NB);
    rowfin_kernel<<<NB, 256, 0, stream>>>(bbaseR, stagingR, sorted, rowptr, dinv, N);  // in-place
    col_finalize_kernel<<<NB * CSL, 256, 0, stream>>>(bbaseC, stagingC, dinv, presum, N); // frees regB
    h1_kernel<<<(N + B - 1) / B, B, 0, stream>>>(x, w1_0, b1, dinv, h1b, h1q, N);
    {
        long t = (long)N * 4;
        gather_kernel<<<(int)((t + B - 1) / B), B, 0, stream>>>(rowptr, sorted, (const uint2*)h1q, p1b, N);
    }
    h2pool_kernel<<<H2B, B, 0, stream>>>(h1b, p1b, presum, dinv, w2_0, w2_1, b2, sbuf, N, H2B * 4);
    final_kernel<<<1, 64, 0, stream>>>(sbuf, w3_0, w3_1, b3, (float*)d_out, 1.0f / (float)N);
}